// Round 3
// baseline (1266.351 us; speedup 1.0000x reference)
//
#include <hip/hip_runtime.h>
#include <math.h>

// Problem constants (fixed shapes from setup_inputs)
#define Dn   12
#define Hn   448
#define Wn   224
#define HWn  (Hn*Wn)        // 100352
#define DHWn (Dn*HWn)       // 1204224
#define Cn   10

// Y1T layout is TILE-MAJOR: slice (c,d) = 56 tiles of [L=0..223][hh=0..7],
// tile t covers rows h = 8t..8t+7. float2 index within slice:
//   t*1792 + L*8 + hh        (tile = 1792 float2 = 14336 B, fully contiguous)
#define TILE_F2 1792

// Twiddle table (float2 in global):
#define TW_W32   0     // 16:  W32^j
#define TW_W7    16    // 7:   W7^j (kept in table but DFT7 uses literals)
#define TW_W64   23    // 32:  W64^j
#define TW_T224  55    // 224: W224^{d7*l32}  [d7*32+l32]
#define TW_T448  279   // 448: W448^{d7*lane} [d7*64+lane]
#define TW_NT    727

// W7^j = exp(-2*pi*i*j/7), compile-time (folds to literals under full unroll)
__device__ __constant__ const float W7R[7] = {
    1.0f,  0.62348980185873359f, -0.22252093395631445f, -0.90096886790241915f,
    -0.90096886790241915f, -0.22252093395631445f, 0.62348980185873359f };
__device__ __constant__ const float W7I[7] = {
    0.0f, -0.78183148246802980f, -0.97492791218182362f, -0.43388373911755823f,
    0.43388373911755823f,  0.97492791218182362f, 0.78183148246802980f };

// ---------- complex helpers ----------
__device__ __forceinline__ float2 cmul(float2 a, float2 b) {
    return make_float2(fmaf(a.x, b.x, -a.y * b.y), fmaf(a.x, b.y, a.y * b.x));
}
__device__ __forceinline__ float2 cfma(float2 a, float2 b, float2 acc) {
    acc.x = fmaf(a.x, b.x, fmaf(-a.y, b.y, acc.x));
    acc.y = fmaf(a.x, b.y, fmaf(a.y, b.x, acc.y));
    return acc;
}
__device__ __forceinline__ float2 cfma_lit(float2 a, float wr, float wi, float2 acc) {
    acc.x = fmaf(a.x, wr, fmaf(-a.y, wi, acc.x));
    acc.y = fmaf(a.x, wi, fmaf(a.y, wr, acc.y));
    return acc;
}
__device__ __forceinline__ float2 cadd(float2 a, float2 b) { return make_float2(a.x + b.x, a.y + b.y); }
__device__ __forceinline__ float2 csub(float2 a, float2 b) { return make_float2(a.x - b.x, a.y - b.y); }
__host__ __device__ constexpr int brev5(int i) {
    return ((i & 1) << 4) | ((i & 2) << 2) | (i & 4) | ((i & 8) >> 2) | ((i & 16) >> 4);
}

__device__ __forceinline__ float2 shflx2(float2 v, int m) {
    return make_float2(__shfl_xor(v.x, m, 64), __shfl_xor(v.y, m, 64));
}

__device__ __forceinline__ double waveReduce(double v) {
#pragma unroll
    for (int o = 32; o > 0; o >>= 1) v += __shfl_down(v, o, 64);
    return v;
}

// ---------- init kernels ----------
__global__ void k_init_misc(float2* __restrict__ tws, double* __restrict__ S) {
    int t = threadIdx.x;  // 1024 threads
    const double PI2 = 6.283185307179586476925287;
    if (t < 16)              { double s, c; sincos(-(PI2 * t) / 32.0, &s, &c); tws[TW_W32 + t] = make_float2((float)c, (float)s); }
    if (t >= 16 && t < 23)   { int j = t - 16; double s, c; sincos(-(PI2 * j) / 7.0,  &s, &c); tws[TW_W7 + j]  = make_float2((float)c, (float)s); }
    if (t >= 23 && t < 55)   { int j = t - 23; double s, c; sincos(-(PI2 * j) / 64.0, &s, &c); tws[TW_W64 + j] = make_float2((float)c, (float)s); }
    if (t >= 55 && t < 279)  { int j = t - 55;  int d7 = j >> 5, l = j & 31;
                               double s, c; sincos(-(PI2 * (d7 * l)) / 224.0, &s, &c);
                               tws[TW_T224 + j] = make_float2((float)c, (float)s); }
    if (t >= 279 && t < 727) { int j = t - 279; int d7 = j >> 6, l = j & 63;
                               double s, c; sincos(-(PI2 * (d7 * l)) / 448.0, &s, &c);
                               tws[TW_T448 + j] = make_float2((float)c, (float)s); }
    if (t >= 727 && t < 759) S[t - 727] = 0.0;
}

__global__ void k_build_p(const float* __restrict__ z, const float* __restrict__ zf,
                          const float* __restrict__ miu,
                          float2* __restrict__ p, float2* __restrict__ r, float2* __restrict__ b,
                          double* __restrict__ S) {
    float mu = fabsf(miu[0]);
    double acc = 0.0;
    for (int e = blockIdx.x * blockDim.x + threadIdx.x; e < DHWn; e += gridDim.x * blockDim.x) {
        int d = e / HWn, rem = e - d * HWn;
        int h = rem / Wn, w = rem - h * Wn;
        int hs = h + Hn / 2; if (hs >= Hn) hs -= Hn;
        int ws = w + Wn / 2; if (ws >= Wn) ws -= Wn;
        int src = d * HWn + hs * Wn + ws;
        float pr = fmaf(mu, z[src], zf[src]);
        float pi = fmaf(mu, z[DHWn + src], zf[DHWn + src]);
        float2 v = make_float2(pr, pi);
        p[e] = v; r[e] = v; b[e] = make_float2(0.f, 0.f);
        acc += (double)pr * pr + (double)pi * pi;
    }
    acc = waveReduce(acc);
    if ((threadIdx.x & 63) == 0) atomicAdd(&S[0], acc);
}

__global__ void k_build_coil(const float* __restrict__ cr, const float* __restrict__ ci,
                             float2* __restrict__ coil) {
    for (int e = blockIdx.x * blockDim.x + threadIdx.x; e < Cn * HWn; e += gridDim.x * blockDim.x) {
        int c = e / HWn, rem = e - c * HWn;
        int h = rem / Wn, w = rem - h * Wn;
        int hs = h + Hn / 2; if (hs >= Hn) hs -= Hn;
        int ws = w + Wn / 2; if (ws >= Wn) ws -= Wn;
        int src = c * HWn + hs * Wn + ws;
        coil[e] = make_float2(cr[src], ci[src]);
    }
}

// permuted + shifted + scaled mask: maskP[L*448 + h], line L holds true
// frequency column w(L) = 7*brev5(L&31) + (L>>5)
__global__ void k_build_mask(const int* __restrict__ mask, float* __restrict__ maskP) {
    for (int e = blockIdx.x * blockDim.x + threadIdx.x; e < HWn; e += gridDim.x * blockDim.x) {
        int L = e / Hn, h = e - L * Hn;
        int w = 7 * brev5(L & 31) + (L >> 5);
        int hs = h + Hn / 2; if (hs >= Hn) hs -= Hn;
        int ws = w + Wn / 2; if (ws >= Wn) ws -= Wn;
        maskP[e] = (float)mask[hs * Wn + ws] * (1.0f / (float)HWn);
    }
}

// ---------- forward row FFT (224 = 7*32 lane-FFT), coil-mul, write Y1T tiles ----------
#define BPITCH 226
__global__ __launch_bounds__(256) void k_rowfft0(const float2* __restrict__ P,
                                                 const float2* __restrict__ coil,
                                                 float2* __restrict__ Y1T,
                                                 const float2* __restrict__ twg,
                                                 int chunkStart) {
    __shared__ float2 buf[8][BPITCH];
    int tid = threadIdx.x;
    int lane = tid & 63, wv = tid >> 6, hi = lane >> 5, l32 = lane & 31;
    int h0 = blockIdx.x * 8, d = blockIdx.y, cz = blockIdx.z;
    int row = h0 + 2 * wv + hi;
    const float2* w32g = twg + TW_W32;
    const float2* t224 = twg + TW_T224;

    const float2* prow = P + (size_t)d * HWn + (size_t)row * Wn;
    const float2* crow = coil + (size_t)(chunkStart + cz) * HWn + (size_t)row * Wn;

    float2 xb[7];
#pragma unroll
    for (int b = 0; b < 7; ++b) xb[b] = cmul(prow[32 * b + l32], crow[32 * b + l32]);

    // DFT7 (literal twiddles)
    float2 y[7];
#pragma unroll
    for (int d7 = 0; d7 < 7; ++d7) {
        float2 s = xb[0];
#pragma unroll
        for (int b = 1; b < 7; ++b) s = cfma_lit(xb[b], W7R[(b * d7) % 7], W7I[(b * d7) % 7], s);
        y[d7] = s;
    }
    // twiddle W224^{l32*d7} from table
#pragma unroll
    for (int d7 = 1; d7 < 7; ++d7) y[d7] = cmul(y[d7], t224[d7 * 32 + l32]);

    // FFT32 across each half-wave, DIF (sign-trick form: y' = (t + s*y)*weff)
#pragma unroll
    for (int s = 0; s < 5; ++s) {
        int dist = 16 >> s;
        float2 wst = w32g[(l32 & (dist - 1)) << s];
        bool h2 = (l32 & dist) != 0;
        float sg = h2 ? -1.f : 1.f;
        float2 weff = h2 ? wst : make_float2(1.f, 0.f);
#pragma unroll
        for (int d7 = 0; d7 < 7; ++d7) {
            float2 t = shflx2(y[d7], dist);
            float2 u = make_float2(fmaf(sg, y[d7].x, t.x), fmaf(sg, y[d7].y, t.y));
            y[d7] = cmul(u, weff);
        }
    }

    // deposit to LDS: line L = d7*32 + l32, row-in-tile = 2wv+hi
#pragma unroll
    for (int d7 = 0; d7 < 7; ++d7) buf[2 * wv + hi][d7 * 32 + l32] = y[d7];
    __syncthreads();

    // tile-major store: fully contiguous 14336 B per block
    float2* tile = Y1T + ((size_t)cz * Dn + d) * (size_t)HWn + (size_t)blockIdx.x * TILE_F2;
#pragma unroll
    for (int k = 0; k < 7; ++k) {
        int i = tid + k * 256;          // element j = L*8+hh within tile
        tile[i] = buf[i & 7][i >> 3];
    }
}

// ---------- column FFT448 + mask + IFFT448 ----------
// 512 threads = 8 waves, 16 lines/block (2 lines per wave). Tile-major global
// accesses staged through LDS so every global segment is >=512 B contiguous.
#define LPITCH 452
__global__ __launch_bounds__(512) void k_colfft(float2* __restrict__ Y1T,
                                                const float* __restrict__ maskP,
                                                const float2* __restrict__ twg) {
    __shared__ float2 ls[16][LPITCH];
    int tid = threadIdx.x;               // 0..511
    int lane = tid & 63, wv = tid >> 6;  // wave wv owns lines L0+wv, L0+8+wv
    int L0 = blockIdx.x * 16;            // 14 blocks in x
    int d = blockIdx.y, cz = blockIdx.z;
    const float2* w64t = twg + TW_W64;
    const float2* t448 = twg + TW_T448;

    float2* base = Y1T + ((size_t)cz * Dn + d) * (size_t)HWn;

    // load: 56 tiles x (16L x 8hh) = 7168 float2, 14 per thread, 512B/wave segments
#pragma unroll
    for (int m = 0; m < 14; ++m) {
        int j = tid + m * 512;
        int t = j >> 7, rem = j & 127;   // rem = ll*8 + hh, ll = 0..15
        ls[rem >> 3][t * 8 + (rem & 7)] = base[(size_t)t * TILE_F2 + (size_t)L0 * 8 + rem];
    }
    __syncthreads();

    // twiddles W448^{lane*d7}, shared by both lines (lane-only dependence)
    float2 tp[7];
#pragma unroll
    for (int d7 = 1; d7 < 7; ++d7) tp[d7] = t448[d7 * 64 + lane];

    float2 y[2][7];
    // forward DFT7 (literal twiddles) + W448 twiddle, per line
#pragma unroll
    for (int ln = 0; ln < 2; ++ln) {
        float2 xb[7];
#pragma unroll
        for (int b = 0; b < 7; ++b) xb[b] = ls[wv + 8 * ln][64 * b + lane];
#pragma unroll
        for (int d7 = 0; d7 < 7; ++d7) {
            float2 s = xb[0];
#pragma unroll
            for (int b = 1; b < 7; ++b) s = cfma_lit(xb[b], W7R[(b * d7) % 7], W7I[(b * d7) % 7], s);
            y[ln][d7] = s;
        }
#pragma unroll
        for (int d7 = 1; d7 < 7; ++d7) y[ln][d7] = cmul(y[ln][d7], tp[d7]);
    }

    // FFT64 across lanes, DIF (sign-trick): y' = (t + s*y) * weff
#pragma unroll
    for (int s = 0; s < 6; ++s) {
        int dist = 32 >> s;
        float2 wst = w64t[(lane & (dist - 1)) << s];
        bool hi = (lane & dist) != 0;
        float sg = hi ? -1.f : 1.f;
        float2 weff = hi ? wst : make_float2(1.f, 0.f);
#pragma unroll
        for (int ln = 0; ln < 2; ++ln)
#pragma unroll
            for (int d7 = 0; d7 < 7; ++d7) {
                float2 t = shflx2(y[ln][d7], dist);
                float2 u = make_float2(fmaf(sg, y[ln][d7].x, t.x), fmaf(sg, y[ln][d7].y, t.y));
                y[ln][d7] = cmul(u, weff);
            }
    }

    // mask: lane holds H-freq index 7*brev6(lane)+d7
    int rb = (brev5(lane & 31) << 1) | (lane >> 5);
#pragma unroll
    for (int ln = 0; ln < 2; ++ln) {
        int L = L0 + wv + 8 * ln;
        const float* mrow = maskP + (size_t)L * Hn + 7 * rb;
#pragma unroll
        for (int d7 = 0; d7 < 7; ++d7) {
            float m = mrow[d7];
            y[ln][d7].x *= m; y[ln][d7].y *= m;
        }
    }

    // inverse FFT64, DIT (sign-trick): y' = A + c*B, c = +-conj(wst)
#pragma unroll
    for (int s = 0; s < 6; ++s) {
        int dist = 1 << s;
        float2 wst = w64t[(lane & (dist - 1)) << (5 - s)];
        wst.y = -wst.y;
        bool hi = (lane & dist) != 0;
        float2 c = hi ? make_float2(-wst.x, -wst.y) : wst;
#pragma unroll
        for (int ln = 0; ln < 2; ++ln)
#pragma unroll
            for (int d7 = 0; d7 < 7; ++d7) {
                float2 t = shflx2(y[ln][d7], dist);
                float2 B = hi ? y[ln][d7] : t;
                float2 A = hi ? t : y[ln][d7];
                y[ln][d7] = cfma(c, B, A);
            }
    }

    // conj W448 twiddle + inverse DFT7 (literal conj twiddles) + LDS writeback
#pragma unroll
    for (int ln = 0; ln < 2; ++ln) {
#pragma unroll
        for (int d7 = 1; d7 < 7; ++d7) {
            float2 c = make_float2(tp[d7].x, -tp[d7].y);
            y[ln][d7] = cmul(y[ln][d7], c);
        }
#pragma unroll
        for (int b = 0; b < 7; ++b) {
            float2 s = y[ln][0];
#pragma unroll
            for (int d7 = 1; d7 < 7; ++d7)
                s = cfma_lit(y[ln][d7], W7R[(b * d7) % 7], -W7I[(b * d7) % 7], s);
            ls[wv + 8 * ln][64 * b + lane] = s;
        }
    }
    __syncthreads();

    // store: same tile-major addressing, fully coalesced
#pragma unroll
    for (int m = 0; m < 14; ++m) {
        int j = tid + m * 512;
        int t = j >> 7, rem = j & 127;
        base[(size_t)t * TILE_F2 + (size_t)L0 * 8 + rem] = ls[rem >> 3][t * 8 + (rem & 7)];
    }
}

// ---------- fused inverse row FFT + conj-coil + coil-sum + q/dot epilogue ----------
// Double-buffered LDS strips; strip loads are contiguous tile reads.
__global__ __launch_bounds__(256) void k_irow_combine(const float2* __restrict__ Y1T,
                                                      const float2* __restrict__ coil,
                                                      const float2* __restrict__ P,
                                                      float2* __restrict__ Q,
                                                      const float* __restrict__ miu,
                                                      double* __restrict__ S,
                                                      const float2* __restrict__ twg,
                                                      int cc, int chunkStart,
                                                      int first, int last, int it) {
    __shared__ float2 buf[2][8][BPITCH];
    __shared__ double sred[8];
    int tid = threadIdx.x;
    int lane = tid & 63, wv = tid >> 6, hi = lane >> 5, l32 = lane & 31;
    int h0 = blockIdx.x * 8, d = blockIdx.y;
    int row = h0 + 2 * wv + hi;
    const float2* w32g = twg + TW_W32;
    const float2* t224 = twg + TW_T224;

    float2 tp[7];
#pragma unroll
    for (int d7 = 1; d7 < 7; ++d7) {
        float2 v = t224[d7 * 32 + l32];
        tp[d7] = make_float2(v.x, -v.y);   // conj (inverse twiddle)
    }

    float2 acc[7];
#pragma unroll
    for (int b = 0; b < 7; ++b) acc[b] = make_float2(0.f, 0.f);

    // stage strip 0 into buf[0] — contiguous tile read
    float2 pre[7];
    {
        const float2* tile0 = Y1T + (size_t)d * HWn + (size_t)blockIdx.x * TILE_F2;
#pragma unroll
        for (int k = 0; k < 7; ++k) pre[k] = tile0[tid + k * 256];
#pragma unroll
        for (int k = 0; k < 7; ++k) {
            int i = tid + k * 256;
            buf[0][i & 7][i >> 3] = pre[k];
        }
    }
    __syncthreads();

    for (int cz = 0; cz < cc; ++cz) {
        int cur = cz & 1;
        // issue this coil's row loads FIRST (used at end of compute)
        const float2* crow = coil + (size_t)(chunkStart + cz) * HWn + (size_t)row * Wn;
        float2 cpre[7];
#pragma unroll
        for (int b = 0; b < 7; ++b) cpre[b] = crow[32 * b + l32];
        // then prefetch next strip (drains only at the ds_write below)
        if (cz + 1 < cc) {
            const float2* tilen = Y1T + ((size_t)(cz + 1) * Dn + d) * (size_t)HWn
                                + (size_t)blockIdx.x * TILE_F2;
#pragma unroll
            for (int k = 0; k < 7; ++k) pre[k] = tilen[tid + k * 256];
        }

        // lane l32 reads line L = d7*32 + l32 (DIT-ready bit-rev order)
        float2 y[7];
#pragma unroll
        for (int d7 = 0; d7 < 7; ++d7) y[d7] = buf[cur][2 * wv + hi][d7 * 32 + l32];

        // inverse FFT32 across half-wave, DIT (sign-trick): y' = A + c*B
#pragma unroll
        for (int s = 0; s < 5; ++s) {
            int dist = 1 << s;
            float2 wst = w32g[(l32 & (dist - 1)) << (4 - s)];
            wst.y = -wst.y;
            bool h2 = (l32 & dist) != 0;
            float2 c = h2 ? make_float2(-wst.x, -wst.y) : wst;
#pragma unroll
            for (int d7 = 0; d7 < 7; ++d7) {
                float2 t = shflx2(y[d7], dist);
                float2 B = h2 ? y[d7] : t;
                float2 A = h2 ? t : y[d7];
                y[d7] = cfma(c, B, A);
            }
        }
        // conj twiddle W224^{-l32*d7}
#pragma unroll
        for (int d7 = 1; d7 < 7; ++d7) y[d7] = cmul(y[d7], tp[d7]);
        // inverse DFT7 (literal conj twiddles) + conj-coil accumulate
#pragma unroll
        for (int b = 0; b < 7; ++b) {
            float2 s = y[0];
#pragma unroll
            for (int d7 = 1; d7 < 7; ++d7)
                s = cfma_lit(y[d7], W7R[(b * d7) % 7], -W7I[(b * d7) % 7], s);
            float2 c = cpre[b];
            acc[b].x += fmaf(s.x, c.x, s.y * c.y);
            acc[b].y += fmaf(s.y, c.x, -s.x * c.y);
        }

        // write next strip into the other buffer, one barrier per coil
        if (cz + 1 < cc) {
#pragma unroll
            for (int k = 0; k < 7; ++k) {
                int i = tid + k * 256;
                buf[cur ^ 1][i & 7][i >> 3] = pre[k];
            }
        }
        __syncthreads();
    }

    // epilogue: q = mu*p + acc (or q += acc), dots on last chunk
    float mu = fabsf(miu[0]);
    const float2* prow = P + (size_t)d * HWn + (size_t)row * Wn;
    float2* qrow = Q + (size_t)d * HWn + (size_t)row * Wn;
    double ar = 0.0, ai = 0.0;
#pragma unroll
    for (int b = 0; b < 7; ++b) {
        float2 pv = prow[32 * b + l32];
        float2 s0;
        if (first) s0 = make_float2(fmaf(mu, pv.x, acc[b].x), fmaf(mu, pv.y, acc[b].y));
        else { float2 qv = qrow[32 * b + l32]; s0 = cadd(qv, acc[b]); }
        qrow[32 * b + l32] = s0;
        if (last) {
            ar += (double)(s0.x * pv.x + s0.y * pv.y);
            ai += (double)(s0.y * pv.x - s0.x * pv.y);
        }
    }
    if (last) {
        ar = waveReduce(ar);
        ai = waveReduce(ai);
        if (lane == 0) { sred[wv] = ar; sred[4 + wv] = ai; }
        __syncthreads();
        if (tid == 0) {
            atomicAdd(&S[8 + it],  sred[0] + sred[1] + sred[2] + sred[3]);
            atomicAdd(&S[16 + it], sred[4] + sred[5] + sred[6] + sred[7]);
        }
    }
}

// ---------- CG scalar updates (float4 = 2 complex per lane) ----------
__global__ void k_update_br(const double* __restrict__ Sin, double* __restrict__ S, int it,
                            const float4* __restrict__ p, const float4* __restrict__ q,
                            float4* __restrict__ b, float4* __restrict__ r) {
    double rr = Sin[it], qr = Sin[8 + it], qi = Sin[16 + it];
    double den = qr * qr + qi * qi;
    float arf = (float)(rr * qr / den);
    float aif = (float)(-rr * qi / den);
    double acc = 0.0;
    const int N2 = DHWn / 2;
    for (int e = blockIdx.x * blockDim.x + threadIdx.x; e < N2; e += gridDim.x * blockDim.x) {
        float4 pv = p[e], qv = q[e], bv = b[e], rv = r[e];
        bv.x += arf * pv.x - aif * pv.y;  bv.y += arf * pv.y + aif * pv.x;
        bv.z += arf * pv.z - aif * pv.w;  bv.w += arf * pv.w + aif * pv.z;
        b[e] = bv;
        rv.x -= arf * qv.x - aif * qv.y;  rv.y -= arf * qv.y + aif * qv.x;
        rv.z -= arf * qv.z - aif * qv.w;  rv.w -= arf * qv.w + aif * qv.z;
        r[e] = rv;
        acc += (double)rv.x * rv.x + (double)rv.y * rv.y
             + (double)rv.z * rv.z + (double)rv.w * rv.w;
    }
    acc = waveReduce(acc);
    if ((threadIdx.x & 63) == 0) atomicAdd(&S[it + 1], acc);
}

__global__ void k_update_p(const double* __restrict__ S, int it,
                           const float4* __restrict__ r, float4* __restrict__ p) {
    float beta = (float)(S[it + 1] / S[it]);
    const int N2 = DHWn / 2;
    for (int e = blockIdx.x * blockDim.x + threadIdx.x; e < N2; e += gridDim.x * blockDim.x) {
        float4 rv = r[e], pv = p[e];
        p[e] = make_float4(fmaf(beta, pv.x, rv.x), fmaf(beta, pv.y, rv.y),
                           fmaf(beta, pv.z, rv.z), fmaf(beta, pv.w, rv.w));
    }
}

__global__ void k_output(const float2* __restrict__ b, float* __restrict__ out) {
    for (int e = blockIdx.x * blockDim.x + threadIdx.x; e < DHWn; e += gridDim.x * blockDim.x) {
        int d = e / HWn, rem = e - d * HWn;
        int h = rem / Wn, w = rem - h * Wn;
        int hs = h + Hn / 2; if (hs >= Hn) hs -= Hn;
        int ws = w + Wn / 2; if (ws >= Wn) ws -= Wn;
        float2 v = b[d * HWn + hs * Wn + ws];
        out[e] = v.x;
        out[DHWn + e] = v.y;
    }
}

extern "C" void kernel_launch(void* const* d_in, const int* in_sizes, int n_in,
                              void* d_out, int out_size, void* d_ws, size_t ws_size,
                              hipStream_t stream) {
    const float* z      = (const float*)d_in[0];
    const float* zf     = (const float*)d_in[1];
    const float* coil_r = (const float*)d_in[2];
    const float* coil_i = (const float*)d_in[3];
    const int*   maskp  = (const int*)d_in[4];
    const float* miu    = (const float*)d_in[5];
    float* out = (float*)d_out;

    char* w = (char*)d_ws;
    size_t off = 0;
    auto carve = [&](size_t bytes) -> void* {
        void* ptr = w + off;
        off += (bytes + 511) & ~(size_t)511;
        return ptr;
    };
    float2* P     = (float2*)carve((size_t)DHWn * 8);
    float2* R     = (float2*)carve((size_t)DHWn * 8);
    float2* Bv    = (float2*)carve((size_t)DHWn * 8);
    float2* Q     = (float2*)carve((size_t)DHWn * 8);
    float2* COIL  = (float2*)carve((size_t)Cn * HWn * 8);
    float*  MASKP = (float*)carve((size_t)HWn * 4);
    float2* TWS   = (float2*)carve(TW_NT * 8);
    double* S     = (double*)carve(64 * 8);

    size_t imgSet = (size_t)DHWn * 8;   // one coil-slot (12 slices), 9.63 MB
    int cc = 1;
    {
        const int opts[4] = {10, 5, 2, 1};
        for (int i = 0; i < 4; ++i) {
            if (off + (size_t)opts[i] * imgSet <= ws_size) { cc = opts[i]; break; }
        }
    }
    float2* Y1T = (float2*)carve((size_t)cc * imgSet);   // staged tiles [c][d][t][L][hh]
    int nch = Cn / cc;

    k_init_misc<<<1, 1024, 0, stream>>>(TWS, S);
    k_build_p<<<1024, 256, 0, stream>>>(z, zf, miu, P, R, Bv, S);
    k_build_coil<<<1024, 256, 0, stream>>>(coil_r, coil_i, COIL);
    k_build_mask<<<512, 256, 0, stream>>>(maskp, MASKP);

    for (int it = 0; it < 5; ++it) {
        for (int ch = 0; ch < nch; ++ch) {
            int cs = ch * cc;
            dim3 gf(Hn / 8, Dn, cc);    // 56 x 12 x cc
            dim3 gc(Wn / 16, Dn, cc);   // 14 x 12 x cc
            dim3 gi(Hn / 8, Dn);        // 56 x 12, loops over cc coils
            k_rowfft0<<<gf, 256, 0, stream>>>(P, COIL, Y1T, TWS, cs);
            k_colfft<<<gc, 512, 0, stream>>>(Y1T, MASKP, TWS);
            k_irow_combine<<<gi, 256, 0, stream>>>(Y1T, COIL, P, Q, miu, S, TWS,
                                                   cc, cs, ch == 0 ? 1 : 0,
                                                   ch == nch - 1 ? 1 : 0, it);
        }
        k_update_br<<<1024, 256, 0, stream>>>(S, S, it, (const float4*)P, (const float4*)Q,
                                              (float4*)Bv, (float4*)R);
        if (it < 4) k_update_p<<<1024, 256, 0, stream>>>(S, it, (const float4*)R, (float4*)P);
    }
    k_output<<<1024, 256, 0, stream>>>(Bv, out);
}

// Round 4
// 1145.339 us; speedup vs baseline: 1.1057x; 1.1057x over previous
//
#include <hip/hip_runtime.h>
#include <math.h>

// Problem constants (fixed shapes from setup_inputs)
#define Dn   12
#define Hn   448
#define Wn   224
#define HWn  (Hn*Wn)        // 100352
#define DHWn (Dn*HWn)       // 1204224
#define Cn   10

// Y1T layout is TILE-MAJOR: slice (c,d) = 56 tiles of [L=0..223][hh=0..7],
// tile t covers rows h = 8t..8t+7. float2 index within slice:
//   t*1792 + L*8 + hh        (tile = 1792 float2 = 14336 B, fully contiguous)
#define TILE_F2 1792

// Twiddle table (float2 in global):
#define TW_W32   0     // 16:  W32^j
#define TW_W7    16    // 7:   W7^j (kept in table but DFT7 uses literals)
#define TW_W64   23    // 32:  W64^j
#define TW_T224  55    // 224: W224^{d7*l32}  [d7*32+l32]
#define TW_T448  279   // 448: W448^{d7*lane} [d7*64+lane]
#define TW_NT    727

// W7^j = exp(-2*pi*i*j/7), compile-time (folds to literals under full unroll)
__device__ __constant__ const float W7R[7] = {
    1.0f,  0.62348980185873359f, -0.22252093395631445f, -0.90096886790241915f,
    -0.90096886790241915f, -0.22252093395631445f, 0.62348980185873359f };
__device__ __constant__ const float W7I[7] = {
    0.0f, -0.78183148246802980f, -0.97492791218182362f, -0.43388373911755823f,
    0.43388373911755823f,  0.97492791218182362f, 0.78183148246802980f };

// ---------- complex helpers ----------
__device__ __forceinline__ float2 cmul(float2 a, float2 b) {
    return make_float2(fmaf(a.x, b.x, -a.y * b.y), fmaf(a.x, b.y, a.y * b.x));
}
__device__ __forceinline__ float2 cfma(float2 a, float2 b, float2 acc) {
    acc.x = fmaf(a.x, b.x, fmaf(-a.y, b.y, acc.x));
    acc.y = fmaf(a.x, b.y, fmaf(a.y, b.x, acc.y));
    return acc;
}
__device__ __forceinline__ float2 cfma_lit(float2 a, float wr, float wi, float2 acc) {
    acc.x = fmaf(a.x, wr, fmaf(-a.y, wi, acc.x));
    acc.y = fmaf(a.x, wi, fmaf(a.y, wr, acc.y));
    return acc;
}
__device__ __forceinline__ float2 cadd(float2 a, float2 b) { return make_float2(a.x + b.x, a.y + b.y); }
__device__ __forceinline__ float2 csub(float2 a, float2 b) { return make_float2(a.x - b.x, a.y - b.y); }
__host__ __device__ constexpr int brev5(int i) {
    return ((i & 1) << 4) | ((i & 2) << 2) | (i & 4) | ((i & 8) >> 2) | ((i & 16) >> 4);
}

__device__ __forceinline__ float2 shflx2(float2 v, int m) {
    return make_float2(__shfl_xor(v.x, m, 64), __shfl_xor(v.y, m, 64));
}

__device__ __forceinline__ double waveReduce(double v) {
#pragma unroll
    for (int o = 32; o > 0; o >>= 1) v += __shfl_down(v, o, 64);
    return v;
}

// ---------- init kernels ----------
__global__ void k_init_misc(float2* __restrict__ tws, double* __restrict__ S) {
    int t = threadIdx.x;  // 1024 threads
    const double PI2 = 6.283185307179586476925287;
    if (t < 16)              { double s, c; sincos(-(PI2 * t) / 32.0, &s, &c); tws[TW_W32 + t] = make_float2((float)c, (float)s); }
    if (t >= 16 && t < 23)   { int j = t - 16; double s, c; sincos(-(PI2 * j) / 7.0,  &s, &c); tws[TW_W7 + j]  = make_float2((float)c, (float)s); }
    if (t >= 23 && t < 55)   { int j = t - 23; double s, c; sincos(-(PI2 * j) / 64.0, &s, &c); tws[TW_W64 + j] = make_float2((float)c, (float)s); }
    if (t >= 55 && t < 279)  { int j = t - 55;  int d7 = j >> 5, l = j & 31;
                               double s, c; sincos(-(PI2 * (d7 * l)) / 224.0, &s, &c);
                               tws[TW_T224 + j] = make_float2((float)c, (float)s); }
    if (t >= 279 && t < 727) { int j = t - 279; int d7 = j >> 6, l = j & 63;
                               double s, c; sincos(-(PI2 * (d7 * l)) / 448.0, &s, &c);
                               tws[TW_T448 + j] = make_float2((float)c, (float)s); }
    if (t >= 727 && t < 759) S[t - 727] = 0.0;
}

__global__ void k_build_p(const float* __restrict__ z, const float* __restrict__ zf,
                          const float* __restrict__ miu,
                          float2* __restrict__ p, float2* __restrict__ r, float2* __restrict__ b,
                          double* __restrict__ S) {
    float mu = fabsf(miu[0]);
    double acc = 0.0;
    for (int e = blockIdx.x * blockDim.x + threadIdx.x; e < DHWn; e += gridDim.x * blockDim.x) {
        int d = e / HWn, rem = e - d * HWn;
        int h = rem / Wn, w = rem - h * Wn;
        int hs = h + Hn / 2; if (hs >= Hn) hs -= Hn;
        int ws = w + Wn / 2; if (ws >= Wn) ws -= Wn;
        int src = d * HWn + hs * Wn + ws;
        float pr = fmaf(mu, z[src], zf[src]);
        float pi = fmaf(mu, z[DHWn + src], zf[DHWn + src]);
        float2 v = make_float2(pr, pi);
        p[e] = v; r[e] = v; b[e] = make_float2(0.f, 0.f);
        acc += (double)pr * pr + (double)pi * pi;
    }
    acc = waveReduce(acc);
    if ((threadIdx.x & 63) == 0) atomicAdd(&S[0], acc);
}

__global__ void k_build_coil(const float* __restrict__ cr, const float* __restrict__ ci,
                             float2* __restrict__ coil) {
    for (int e = blockIdx.x * blockDim.x + threadIdx.x; e < Cn * HWn; e += gridDim.x * blockDim.x) {
        int c = e / HWn, rem = e - c * HWn;
        int h = rem / Wn, w = rem - h * Wn;
        int hs = h + Hn / 2; if (hs >= Hn) hs -= Hn;
        int ws = w + Wn / 2; if (ws >= Wn) ws -= Wn;
        int src = c * HWn + hs * Wn + ws;
        coil[e] = make_float2(cr[src], ci[src]);
    }
}

// permuted + shifted + scaled mask: maskP[L*448 + h], line L holds true
// frequency column w(L) = 7*brev5(L&31) + (L>>5)
__global__ void k_build_mask(const int* __restrict__ mask, float* __restrict__ maskP) {
    for (int e = blockIdx.x * blockDim.x + threadIdx.x; e < HWn; e += gridDim.x * blockDim.x) {
        int L = e / Hn, h = e - L * Hn;
        int w = 7 * brev5(L & 31) + (L >> 5);
        int hs = h + Hn / 2; if (hs >= Hn) hs -= Hn;
        int ws = w + Wn / 2; if (ws >= Wn) ws -= Wn;
        maskP[e] = (float)mask[hs * Wn + ws] * (1.0f / (float)HWn);
    }
}

// ---------- forward row FFT (224 = 7*32 lane-FFT), coil-mul, write Y1T tiles ----------
#define BPITCH 226
__global__ __launch_bounds__(256) void k_rowfft0(const float2* __restrict__ P,
                                                 const float2* __restrict__ coil,
                                                 float2* __restrict__ Y1T,
                                                 const float2* __restrict__ twg,
                                                 int chunkStart) {
    __shared__ float2 buf[8][BPITCH];
    int tid = threadIdx.x;
    int lane = tid & 63, wv = tid >> 6, hi = lane >> 5, l32 = lane & 31;
    int h0 = blockIdx.x * 8, d = blockIdx.y, cz = blockIdx.z;
    int row = h0 + 2 * wv + hi;
    const float2* w32g = twg + TW_W32;
    const float2* t224 = twg + TW_T224;

    const float2* prow = P + (size_t)d * HWn + (size_t)row * Wn;
    const float2* crow = coil + (size_t)(chunkStart + cz) * HWn + (size_t)row * Wn;

    float2 xb[7];
#pragma unroll
    for (int b = 0; b < 7; ++b) xb[b] = cmul(prow[32 * b + l32], crow[32 * b + l32]);

    // DFT7 (literal twiddles)
    float2 y[7];
#pragma unroll
    for (int d7 = 0; d7 < 7; ++d7) {
        float2 s = xb[0];
#pragma unroll
        for (int b = 1; b < 7; ++b) s = cfma_lit(xb[b], W7R[(b * d7) % 7], W7I[(b * d7) % 7], s);
        y[d7] = s;
    }
    // twiddle W224^{l32*d7} from table
#pragma unroll
    for (int d7 = 1; d7 < 7; ++d7) y[d7] = cmul(y[d7], t224[d7 * 32 + l32]);

    // FFT32 across each half-wave, DIF (sign-trick form: y' = (t + s*y)*weff)
#pragma unroll
    for (int s = 0; s < 5; ++s) {
        int dist = 16 >> s;
        float2 wst = w32g[(l32 & (dist - 1)) << s];
        bool h2 = (l32 & dist) != 0;
        float sg = h2 ? -1.f : 1.f;
        float2 weff = h2 ? wst : make_float2(1.f, 0.f);
#pragma unroll
        for (int d7 = 0; d7 < 7; ++d7) {
            float2 t = shflx2(y[d7], dist);
            float2 u = make_float2(fmaf(sg, y[d7].x, t.x), fmaf(sg, y[d7].y, t.y));
            y[d7] = cmul(u, weff);
        }
    }

    // deposit to LDS: line L = d7*32 + l32, row-in-tile = 2wv+hi
#pragma unroll
    for (int d7 = 0; d7 < 7; ++d7) buf[2 * wv + hi][d7 * 32 + l32] = y[d7];
    __syncthreads();

    // tile-major store: fully contiguous 14336 B per block
    float2* tile = Y1T + ((size_t)cz * Dn + d) * (size_t)HWn + (size_t)blockIdx.x * TILE_F2;
#pragma unroll
    for (int k = 0; k < 7; ++k) {
        int i = tid + k * 256;          // element j = L*8+hh within tile
        tile[i] = buf[i & 7][i >> 3];
    }
}

// ---------- column FFT448 + mask + IFFT448 ----------
// 512 threads = 8 waves, 8 lines/block (1 line per wave). Tile-major global
// accesses staged through LDS so every global segment is >=512 B contiguous.
// LPITCH%16==8 makes the staging transpose hit all 16 bank-pairs per
// 16-lane quarter (conflict-free); body accesses are conflict-free for any pitch.
#define LPITCH 456
__global__ __launch_bounds__(512) void k_colfft(float2* __restrict__ Y1T,
                                                const float* __restrict__ maskP,
                                                const float2* __restrict__ twg) {
    __shared__ float2 ls[8][LPITCH];
    int tid = threadIdx.x;               // 0..511
    int lane = tid & 63, wv = tid >> 6;  // wave wv owns line L0+wv
    int L0 = blockIdx.x * 8;             // 28 blocks in x
    int d = blockIdx.y, cz = blockIdx.z;
    const float2* w64t = twg + TW_W64;
    const float2* t448 = twg + TW_T448;

    float2* base = Y1T + ((size_t)cz * Dn + d) * (size_t)HWn;

    // load: 56 tiles x (8L x 8hh) = 3584 float2, 7 per thread, 512B/wave segments
#pragma unroll
    for (int m = 0; m < 7; ++m) {
        int j = tid + m * 512;
        int t = j >> 6, rem = j & 63;    // rem = l*8 + hh
        ls[rem >> 3][t * 8 + (rem & 7)] = base[(size_t)t * TILE_F2 + (size_t)L0 * 8 + rem];
    }
    __syncthreads();

    int L = L0 + wv;

    float2 xb[7];
#pragma unroll
    for (int b = 0; b < 7; ++b) xb[b] = ls[wv][64 * b + lane];

    // twiddles W448^{lane*d7} (reused conjugated in the inverse pass)
    float2 tp[7];
#pragma unroll
    for (int d7 = 1; d7 < 7; ++d7) tp[d7] = t448[d7 * 64 + lane];

    // forward DFT7 (literal twiddles)
    float2 y[7];
#pragma unroll
    for (int d7 = 0; d7 < 7; ++d7) {
        float2 s = xb[0];
#pragma unroll
        for (int b = 1; b < 7; ++b) s = cfma_lit(xb[b], W7R[(b * d7) % 7], W7I[(b * d7) % 7], s);
        y[d7] = s;
    }
#pragma unroll
    for (int d7 = 1; d7 < 7; ++d7) y[d7] = cmul(y[d7], tp[d7]);

    // FFT64 across lanes, DIF (sign-trick): y' = (t + s*y) * weff
#pragma unroll
    for (int s = 0; s < 6; ++s) {
        int dist = 32 >> s;
        float2 wst = w64t[(lane & (dist - 1)) << s];
        bool hi = (lane & dist) != 0;
        float sg = hi ? -1.f : 1.f;
        float2 weff = hi ? wst : make_float2(1.f, 0.f);
#pragma unroll
        for (int d7 = 0; d7 < 7; ++d7) {
            float2 t = shflx2(y[d7], dist);
            float2 u = make_float2(fmaf(sg, y[d7].x, t.x), fmaf(sg, y[d7].y, t.y));
            y[d7] = cmul(u, weff);
        }
    }

    // mask: lane holds H-freq index 7*brev6(lane)+d7
    int rb = (brev5(lane & 31) << 1) | (lane >> 5);
    const float* mrow = maskP + (size_t)L * Hn + 7 * rb;
#pragma unroll
    for (int d7 = 0; d7 < 7; ++d7) {
        float m = mrow[d7];
        y[d7].x *= m; y[d7].y *= m;
    }

    // inverse FFT64, DIT (sign-trick): y' = A + c*B, c = +-conj(wst)
#pragma unroll
    for (int s = 0; s < 6; ++s) {
        int dist = 1 << s;
        float2 wst = w64t[(lane & (dist - 1)) << (5 - s)];
        wst.y = -wst.y;
        bool hi = (lane & dist) != 0;
        float2 c = hi ? make_float2(-wst.x, -wst.y) : wst;
#pragma unroll
        for (int d7 = 0; d7 < 7; ++d7) {
            float2 t = shflx2(y[d7], dist);
            float2 B = hi ? y[d7] : t;
            float2 A = hi ? t : y[d7];
            y[d7] = cfma(c, B, A);
        }
    }
    // conj W448 twiddle + inverse DFT7 (literal conj twiddles) + LDS writeback
#pragma unroll
    for (int d7 = 1; d7 < 7; ++d7) {
        float2 c = make_float2(tp[d7].x, -tp[d7].y);
        y[d7] = cmul(y[d7], c);
    }
#pragma unroll
    for (int b = 0; b < 7; ++b) {
        float2 s = y[0];
#pragma unroll
        for (int d7 = 1; d7 < 7; ++d7)
            s = cfma_lit(y[d7], W7R[(b * d7) % 7], -W7I[(b * d7) % 7], s);
        ls[wv][64 * b + lane] = s;
    }
    __syncthreads();

    // store: same tile-major addressing, fully coalesced
#pragma unroll
    for (int m = 0; m < 7; ++m) {
        int j = tid + m * 512;
        int t = j >> 6, rem = j & 63;
        base[(size_t)t * TILE_F2 + (size_t)L0 * 8 + rem] = ls[rem >> 3][t * 8 + (rem & 7)];
    }
}

// ---------- fused inverse row FFT + conj-coil + coil-sum + q/dot epilogue ----------
// Double-buffered LDS strips; strip loads are contiguous tile reads.
__global__ __launch_bounds__(256) void k_irow_combine(const float2* __restrict__ Y1T,
                                                      const float2* __restrict__ coil,
                                                      const float2* __restrict__ P,
                                                      float2* __restrict__ Q,
                                                      const float* __restrict__ miu,
                                                      double* __restrict__ S,
                                                      const float2* __restrict__ twg,
                                                      int cc, int chunkStart,
                                                      int first, int last, int it) {
    __shared__ float2 buf[2][8][BPITCH];
    __shared__ double sred[8];
    int tid = threadIdx.x;
    int lane = tid & 63, wv = tid >> 6, hi = lane >> 5, l32 = lane & 31;
    int h0 = blockIdx.x * 8, d = blockIdx.y;
    int row = h0 + 2 * wv + hi;
    const float2* w32g = twg + TW_W32;
    const float2* t224 = twg + TW_T224;

    float2 tp[7];
#pragma unroll
    for (int d7 = 1; d7 < 7; ++d7) {
        float2 v = t224[d7 * 32 + l32];
        tp[d7] = make_float2(v.x, -v.y);   // conj (inverse twiddle)
    }

    float2 acc[7];
#pragma unroll
    for (int b = 0; b < 7; ++b) acc[b] = make_float2(0.f, 0.f);

    // stage strip 0 into buf[0] — contiguous tile read
    float2 pre[7];
    {
        const float2* tile0 = Y1T + (size_t)d * HWn + (size_t)blockIdx.x * TILE_F2;
#pragma unroll
        for (int k = 0; k < 7; ++k) pre[k] = tile0[tid + k * 256];
#pragma unroll
        for (int k = 0; k < 7; ++k) {
            int i = tid + k * 256;
            buf[0][i & 7][i >> 3] = pre[k];
        }
    }
    __syncthreads();

    for (int cz = 0; cz < cc; ++cz) {
        int cur = cz & 1;
        // issue this coil's row loads FIRST (used at end of compute)
        const float2* crow = coil + (size_t)(chunkStart + cz) * HWn + (size_t)row * Wn;
        float2 cpre[7];
#pragma unroll
        for (int b = 0; b < 7; ++b) cpre[b] = crow[32 * b + l32];
        // then prefetch next strip (drains only at the ds_write below)
        if (cz + 1 < cc) {
            const float2* tilen = Y1T + ((size_t)(cz + 1) * Dn + d) * (size_t)HWn
                                + (size_t)blockIdx.x * TILE_F2;
#pragma unroll
            for (int k = 0; k < 7; ++k) pre[k] = tilen[tid + k * 256];
        }

        // lane l32 reads line L = d7*32 + l32 (DIT-ready bit-rev order)
        float2 y[7];
#pragma unroll
        for (int d7 = 0; d7 < 7; ++d7) y[d7] = buf[cur][2 * wv + hi][d7 * 32 + l32];

        // inverse FFT32 across half-wave, DIT (sign-trick): y' = A + c*B
#pragma unroll
        for (int s = 0; s < 5; ++s) {
            int dist = 1 << s;
            float2 wst = w32g[(l32 & (dist - 1)) << (4 - s)];
            wst.y = -wst.y;
            bool h2 = (l32 & dist) != 0;
            float2 c = h2 ? make_float2(-wst.x, -wst.y) : wst;
#pragma unroll
            for (int d7 = 0; d7 < 7; ++d7) {
                float2 t = shflx2(y[d7], dist);
                float2 B = h2 ? y[d7] : t;
                float2 A = h2 ? t : y[d7];
                y[d7] = cfma(c, B, A);
            }
        }
        // conj twiddle W224^{-l32*d7}
#pragma unroll
        for (int d7 = 1; d7 < 7; ++d7) y[d7] = cmul(y[d7], tp[d7]);
        // inverse DFT7 (literal conj twiddles) + conj-coil accumulate
#pragma unroll
        for (int b = 0; b < 7; ++b) {
            float2 s = y[0];
#pragma unroll
            for (int d7 = 1; d7 < 7; ++d7)
                s = cfma_lit(y[d7], W7R[(b * d7) % 7], -W7I[(b * d7) % 7], s);
            float2 c = cpre[b];
            acc[b].x += fmaf(s.x, c.x, s.y * c.y);
            acc[b].y += fmaf(s.y, c.x, -s.x * c.y);
        }

        // write next strip into the other buffer, one barrier per coil
        if (cz + 1 < cc) {
#pragma unroll
            for (int k = 0; k < 7; ++k) {
                int i = tid + k * 256;
                buf[cur ^ 1][i & 7][i >> 3] = pre[k];
            }
        }
        __syncthreads();
    }

    // epilogue: q = mu*p + acc (or q += acc), dots on last chunk
    float mu = fabsf(miu[0]);
    const float2* prow = P + (size_t)d * HWn + (size_t)row * Wn;
    float2* qrow = Q + (size_t)d * HWn + (size_t)row * Wn;
    double ar = 0.0, ai = 0.0;
#pragma unroll
    for (int b = 0; b < 7; ++b) {
        float2 pv = prow[32 * b + l32];
        float2 s0;
        if (first) s0 = make_float2(fmaf(mu, pv.x, acc[b].x), fmaf(mu, pv.y, acc[b].y));
        else { float2 qv = qrow[32 * b + l32]; s0 = cadd(qv, acc[b]); }
        qrow[32 * b + l32] = s0;
        if (last) {
            ar += (double)(s0.x * pv.x + s0.y * pv.y);
            ai += (double)(s0.y * pv.x - s0.x * pv.y);
        }
    }
    if (last) {
        ar = waveReduce(ar);
        ai = waveReduce(ai);
        if (lane == 0) { sred[wv] = ar; sred[4 + wv] = ai; }
        __syncthreads();
        if (tid == 0) {
            atomicAdd(&S[8 + it],  sred[0] + sred[1] + sred[2] + sred[3]);
            atomicAdd(&S[16 + it], sred[4] + sred[5] + sred[6] + sred[7]);
        }
    }
}

// ---------- CG scalar updates (float4 = 2 complex per lane) ----------
__global__ void k_update_br(const double* __restrict__ Sin, double* __restrict__ S, int it,
                            const float4* __restrict__ p, const float4* __restrict__ q,
                            float4* __restrict__ b, float4* __restrict__ r) {
    double rr = Sin[it], qr = Sin[8 + it], qi = Sin[16 + it];
    double den = qr * qr + qi * qi;
    float arf = (float)(rr * qr / den);
    float aif = (float)(-rr * qi / den);
    double acc = 0.0;
    const int N2 = DHWn / 2;
    for (int e = blockIdx.x * blockDim.x + threadIdx.x; e < N2; e += gridDim.x * blockDim.x) {
        float4 pv = p[e], qv = q[e], bv = b[e], rv = r[e];
        bv.x += arf * pv.x - aif * pv.y;  bv.y += arf * pv.y + aif * pv.x;
        bv.z += arf * pv.z - aif * pv.w;  bv.w += arf * pv.w + aif * pv.z;
        b[e] = bv;
        rv.x -= arf * qv.x - aif * qv.y;  rv.y -= arf * qv.y + aif * qv.x;
        rv.z -= arf * qv.z - aif * qv.w;  rv.w -= arf * qv.w + aif * qv.z;
        r[e] = rv;
        acc += (double)rv.x * rv.x + (double)rv.y * rv.y
             + (double)rv.z * rv.z + (double)rv.w * rv.w;
    }
    acc = waveReduce(acc);
    if ((threadIdx.x & 63) == 0) atomicAdd(&S[it + 1], acc);
}

__global__ void k_update_p(const double* __restrict__ S, int it,
                           const float4* __restrict__ r, float4* __restrict__ p) {
    float beta = (float)(S[it + 1] / S[it]);
    const int N2 = DHWn / 2;
    for (int e = blockIdx.x * blockDim.x + threadIdx.x; e < N2; e += gridDim.x * blockDim.x) {
        float4 rv = r[e], pv = p[e];
        p[e] = make_float4(fmaf(beta, pv.x, rv.x), fmaf(beta, pv.y, rv.y),
                           fmaf(beta, pv.z, rv.z), fmaf(beta, pv.w, rv.w));
    }
}

__global__ void k_output(const float2* __restrict__ b, float* __restrict__ out) {
    for (int e = blockIdx.x * blockDim.x + threadIdx.x; e < DHWn; e += gridDim.x * blockDim.x) {
        int d = e / HWn, rem = e - d * HWn;
        int h = rem / Wn, w = rem - h * Wn;
        int hs = h + Hn / 2; if (hs >= Hn) hs -= Hn;
        int ws = w + Wn / 2; if (ws >= Wn) ws -= Wn;
        float2 v = b[d * HWn + hs * Wn + ws];
        out[e] = v.x;
        out[DHWn + e] = v.y;
    }
}

extern "C" void kernel_launch(void* const* d_in, const int* in_sizes, int n_in,
                              void* d_out, int out_size, void* d_ws, size_t ws_size,
                              hipStream_t stream) {
    const float* z      = (const float*)d_in[0];
    const float* zf     = (const float*)d_in[1];
    const float* coil_r = (const float*)d_in[2];
    const float* coil_i = (const float*)d_in[3];
    const int*   maskp  = (const int*)d_in[4];
    const float* miu    = (const float*)d_in[5];
    float* out = (float*)d_out;

    char* w = (char*)d_ws;
    size_t off = 0;
    auto carve = [&](size_t bytes) -> void* {
        void* ptr = w + off;
        off += (bytes + 511) & ~(size_t)511;
        return ptr;
    };
    float2* P     = (float2*)carve((size_t)DHWn * 8);
    float2* R     = (float2*)carve((size_t)DHWn * 8);
    float2* Bv    = (float2*)carve((size_t)DHWn * 8);
    float2* Q     = (float2*)carve((size_t)DHWn * 8);
    float2* COIL  = (float2*)carve((size_t)Cn * HWn * 8);
    float*  MASKP = (float*)carve((size_t)HWn * 4);
    float2* TWS   = (float2*)carve(TW_NT * 8);
    double* S     = (double*)carve(64 * 8);

    size_t imgSet = (size_t)DHWn * 8;   // one coil-slot (12 slices), 9.63 MB
    int cc = 1;
    {
        const int opts[4] = {10, 5, 2, 1};
        for (int i = 0; i < 4; ++i) {
            if (off + (size_t)opts[i] * imgSet <= ws_size) { cc = opts[i]; break; }
        }
    }
    float2* Y1T = (float2*)carve((size_t)cc * imgSet);   // staged tiles [c][d][t][L][hh]
    int nch = Cn / cc;

    k_init_misc<<<1, 1024, 0, stream>>>(TWS, S);
    k_build_p<<<1024, 256, 0, stream>>>(z, zf, miu, P, R, Bv, S);
    k_build_coil<<<1024, 256, 0, stream>>>(coil_r, coil_i, COIL);
    k_build_mask<<<512, 256, 0, stream>>>(maskp, MASKP);

    for (int it = 0; it < 5; ++it) {
        for (int ch = 0; ch < nch; ++ch) {
            int cs = ch * cc;
            dim3 gf(Hn / 8, Dn, cc);    // 56 x 12 x cc
            dim3 gc(Wn / 8, Dn, cc);    // 28 x 12 x cc
            dim3 gi(Hn / 8, Dn);        // 56 x 12, loops over cc coils
            k_rowfft0<<<gf, 256, 0, stream>>>(P, COIL, Y1T, TWS, cs);
            k_colfft<<<gc, 512, 0, stream>>>(Y1T, MASKP, TWS);
            k_irow_combine<<<gi, 256, 0, stream>>>(Y1T, COIL, P, Q, miu, S, TWS,
                                                   cc, cs, ch == 0 ? 1 : 0,
                                                   ch == nch - 1 ? 1 : 0, it);
        }
        k_update_br<<<1024, 256, 0, stream>>>(S, S, it, (const float4*)P, (const float4*)Q,
                                              (float4*)Bv, (float4*)R);
        if (it < 4) k_update_p<<<1024, 256, 0, stream>>>(S, it, (const float4*)R, (float4*)P);
    }
    k_output<<<1024, 256, 0, stream>>>(Bv, out);
}

// Round 6
// 1136.842 us; speedup vs baseline: 1.1139x; 1.0075x over previous
//
#include <hip/hip_runtime.h>
#include <math.h>

// Problem constants (fixed shapes from setup_inputs)
#define Dn   12
#define Hn   448
#define Wn   224
#define HWn  (Hn*Wn)        // 100352
#define DHWn (Dn*HWn)       // 1204224
#define Cn   10

// Y1T layout is TILE-MAJOR: slice (c,d) = 56 tiles of [L=0..223][hh=0..7],
// tile t covers rows h = 8t..8t+7. float2 index within slice:
//   t*1792 + L*8 + hh        (tile = 1792 float2 = 14336 B, fully contiguous)
#define TILE_F2 1792

// Twiddle table (float2 in global):
#define TW_W32   0     // 16:  W32^j
#define TW_W7    16    // 7:   W7^j (kept in table but DFT7 uses literals)
#define TW_W64   23    // 32:  W64^j
#define TW_T224  55    // 224: W224^{d7*l32}  [d7*32+l32]
#define TW_T448  279   // 448: W448^{d7*lane} [d7*64+lane]
#define TW_NT    727

// W7^j = exp(-2*pi*i*j/7), compile-time (folds to literals under full unroll)
__device__ __constant__ const float W7R[7] = {
    1.0f,  0.62348980185873359f, -0.22252093395631445f, -0.90096886790241915f,
    -0.90096886790241915f, -0.22252093395631445f, 0.62348980185873359f };
__device__ __constant__ const float W7I[7] = {
    0.0f, -0.78183148246802980f, -0.97492791218182362f, -0.43388373911755823f,
    0.43388373911755823f,  0.97492791218182362f, 0.78183148246802980f };

// ---------- complex helpers ----------
__device__ __forceinline__ float2 cmul(float2 a, float2 b) {
    return make_float2(fmaf(a.x, b.x, -a.y * b.y), fmaf(a.x, b.y, a.y * b.x));
}
__device__ __forceinline__ float2 cfma(float2 a, float2 b, float2 acc) {
    acc.x = fmaf(a.x, b.x, fmaf(-a.y, b.y, acc.x));
    acc.y = fmaf(a.x, b.y, fmaf(a.y, b.x, acc.y));
    return acc;
}
__device__ __forceinline__ float2 cfma_lit(float2 a, float wr, float wi, float2 acc) {
    acc.x = fmaf(a.x, wr, fmaf(-a.y, wi, acc.x));
    acc.y = fmaf(a.x, wi, fmaf(a.y, wr, acc.y));
    return acc;
}
__device__ __forceinline__ float2 cadd(float2 a, float2 b) { return make_float2(a.x + b.x, a.y + b.y); }
__device__ __forceinline__ float2 csub(float2 a, float2 b) { return make_float2(a.x - b.x, a.y - b.y); }
__host__ __device__ constexpr int brev5(int i) {
    return ((i & 1) << 4) | ((i & 2) << 2) | (i & 4) | ((i & 8) >> 2) | ((i & 16) >> 4);
}

__device__ __forceinline__ float2 shflx2(float2 v, int m) {
    return make_float2(__shfl_xor(v.x, m, 64), __shfl_xor(v.y, m, 64));
}

__device__ __forceinline__ double waveReduce(double v) {
#pragma unroll
    for (int o = 32; o > 0; o >>= 1) v += __shfl_down(v, o, 64);
    return v;
}

// ---------- init kernels ----------
__global__ void k_init_misc(float2* __restrict__ tws, double* __restrict__ S) {
    int t = threadIdx.x;  // 1024 threads
    const double PI2 = 6.283185307179586476925287;
    if (t < 16)              { double s, c; sincos(-(PI2 * t) / 32.0, &s, &c); tws[TW_W32 + t] = make_float2((float)c, (float)s); }
    if (t >= 16 && t < 23)   { int j = t - 16; double s, c; sincos(-(PI2 * j) / 7.0,  &s, &c); tws[TW_W7 + j]  = make_float2((float)c, (float)s); }
    if (t >= 23 && t < 55)   { int j = t - 23; double s, c; sincos(-(PI2 * j) / 64.0, &s, &c); tws[TW_W64 + j] = make_float2((float)c, (float)s); }
    if (t >= 55 && t < 279)  { int j = t - 55;  int d7 = j >> 5, l = j & 31;
                               double s, c; sincos(-(PI2 * (d7 * l)) / 224.0, &s, &c);
                               tws[TW_T224 + j] = make_float2((float)c, (float)s); }
    if (t >= 279 && t < 727) { int j = t - 279; int d7 = j >> 6, l = j & 63;
                               double s, c; sincos(-(PI2 * (d7 * l)) / 448.0, &s, &c);
                               tws[TW_T448 + j] = make_float2((float)c, (float)s); }
    if (t >= 727 && t < 759) S[t - 727] = 0.0;
}

__global__ void k_build_p(const float* __restrict__ z, const float* __restrict__ zf,
                          const float* __restrict__ miu,
                          float2* __restrict__ p, float2* __restrict__ r, float2* __restrict__ b,
                          double* __restrict__ S) {
    float mu = fabsf(miu[0]);
    double acc = 0.0;
    for (int e = blockIdx.x * blockDim.x + threadIdx.x; e < DHWn; e += gridDim.x * blockDim.x) {
        int d = e / HWn, rem = e - d * HWn;
        int h = rem / Wn, w = rem - h * Wn;
        int hs = h + Hn / 2; if (hs >= Hn) hs -= Hn;
        int ws = w + Wn / 2; if (ws >= Wn) ws -= Wn;
        int src = d * HWn + hs * Wn + ws;
        float pr = fmaf(mu, z[src], zf[src]);
        float pi = fmaf(mu, z[DHWn + src], zf[DHWn + src]);
        float2 v = make_float2(pr, pi);
        p[e] = v; r[e] = v; b[e] = make_float2(0.f, 0.f);
        acc += (double)pr * pr + (double)pi * pi;
    }
    acc = waveReduce(acc);
    if ((threadIdx.x & 63) == 0) atomicAdd(&S[0], acc);
}

__global__ void k_build_coil(const float* __restrict__ cr, const float* __restrict__ ci,
                             float2* __restrict__ coil) {
    for (int e = blockIdx.x * blockDim.x + threadIdx.x; e < Cn * HWn; e += gridDim.x * blockDim.x) {
        int c = e / HWn, rem = e - c * HWn;
        int h = rem / Wn, w = rem - h * Wn;
        int hs = h + Hn / 2; if (hs >= Hn) hs -= Hn;
        int ws = w + Wn / 2; if (ws >= Wn) ws -= Wn;
        int src = c * HWn + hs * Wn + ws;
        coil[e] = make_float2(cr[src], ci[src]);
    }
}

// permuted + shifted + scaled mask: maskP[L*448 + h], line L holds true
// frequency column w(L) = 7*brev5(L&31) + (L>>5)
__global__ void k_build_mask(const int* __restrict__ mask, float* __restrict__ maskP) {
    for (int e = blockIdx.x * blockDim.x + threadIdx.x; e < HWn; e += gridDim.x * blockDim.x) {
        int L = e / Hn, h = e - L * Hn;
        int w = 7 * brev5(L & 31) + (L >> 5);
        int hs = h + Hn / 2; if (hs >= Hn) hs -= Hn;
        int ws = w + Wn / 2; if (ws >= Wn) ws -= Wn;
        maskP[e] = (float)mask[hs * Wn + ws] * (1.0f / (float)HWn);
    }
}

// ---------- forward row FFT (224 = 7*32 lane-FFT), coil-mul, write Y1T tiles ----------
#define BPITCH 226
__global__ __launch_bounds__(256) void k_rowfft0(const float2* __restrict__ P,
                                                 const float2* __restrict__ coil,
                                                 float2* __restrict__ Y1T,
                                                 const float2* __restrict__ twg,
                                                 int chunkStart) {
    __shared__ float2 buf[8][BPITCH];
    int tid = threadIdx.x;
    int lane = tid & 63, wv = tid >> 6, hi = lane >> 5, l32 = lane & 31;
    int h0 = blockIdx.x * 8, d = blockIdx.y, cz = blockIdx.z;
    int row = h0 + 2 * wv + hi;
    const float2* w32g = twg + TW_W32;
    const float2* t224 = twg + TW_T224;

    const float2* prow = P + (size_t)d * HWn + (size_t)row * Wn;
    const float2* crow = coil + (size_t)(chunkStart + cz) * HWn + (size_t)row * Wn;

    float2 xb[7];
#pragma unroll
    for (int b = 0; b < 7; ++b) xb[b] = cmul(prow[32 * b + l32], crow[32 * b + l32]);

    // DFT7 (literal twiddles)
    float2 y[7];
#pragma unroll
    for (int d7 = 0; d7 < 7; ++d7) {
        float2 s = xb[0];
#pragma unroll
        for (int b = 1; b < 7; ++b) s = cfma_lit(xb[b], W7R[(b * d7) % 7], W7I[(b * d7) % 7], s);
        y[d7] = s;
    }
    // twiddle W224^{l32*d7} from table
#pragma unroll
    for (int d7 = 1; d7 < 7; ++d7) y[d7] = cmul(y[d7], t224[d7 * 32 + l32]);

    // FFT32 across each half-wave, DIF (sign-trick form: y' = (t + s*y)*weff)
#pragma unroll
    for (int s = 0; s < 5; ++s) {
        int dist = 16 >> s;
        float2 wst = w32g[(l32 & (dist - 1)) << s];
        bool h2 = (l32 & dist) != 0;
        float sg = h2 ? -1.f : 1.f;
        float2 weff = h2 ? wst : make_float2(1.f, 0.f);
#pragma unroll
        for (int d7 = 0; d7 < 7; ++d7) {
            float2 t = shflx2(y[d7], dist);
            float2 u = make_float2(fmaf(sg, y[d7].x, t.x), fmaf(sg, y[d7].y, t.y));
            y[d7] = cmul(u, weff);
        }
    }

    // deposit to LDS: line L = d7*32 + l32, row-in-tile = 2wv+hi
#pragma unroll
    for (int d7 = 0; d7 < 7; ++d7) buf[2 * wv + hi][d7 * 32 + l32] = y[d7];
    __syncthreads();

    // tile-major store: fully contiguous 14336 B per block
    float2* tile = Y1T + ((size_t)cz * Dn + d) * (size_t)HWn + (size_t)blockIdx.x * TILE_F2;
#pragma unroll
    for (int k = 0; k < 7; ++k) {
        int i = tid + k * 256;          // element j = L*8+hh within tile
        tile[i] = buf[i & 7][i >> 3];
    }
}

// ---------- column FFT448 + mask + IFFT448 ----------
// 256 threads = 4 waves, 4 lines/block (1 line per wave). 14.6 KB LDS ->
// up to 8 blocks/CU (wave-slot cap), ~2x the resident waves of the 512-thr
// version. Staging is float4 (pairs never straddle tiles; LDS cols adjacent).
// LPITCH%16==8 keeps the staging transpose conflict-free.
#define LPITCH 456
__global__ __launch_bounds__(256) void k_colfft(float2* __restrict__ Y1T,
                                                const float* __restrict__ maskP,
                                                const float2* __restrict__ twg) {
    __shared__ float2 ls[4][LPITCH];
    int tid = threadIdx.x;               // 0..255
    int lane = tid & 63, wv = tid >> 6;  // wave wv owns line L0+wv
    int L0 = blockIdx.x * 4;             // 56 blocks in x
    int d = blockIdx.y, cz = blockIdx.z;
    const float2* w64t = twg + TW_W64;
    const float2* t448 = twg + TW_T448;

    float2* base = Y1T + ((size_t)cz * Dn + d) * (size_t)HWn;

    // load: 56 tiles x (4L x 8hh) = 1792 float2 = 896 float4
#pragma unroll
    for (int m = 0; m < 4; ++m) {
        int j4 = tid + m * 256;
        if (j4 < 896) {
            int t = j4 >> 4, rem4 = j4 & 15;     // 16 f4 per tile-chunk
            int rem = 2 * rem4;                  // f2 index: l*8 + hh (even)
            float4 v = *(const float4*)&base[(size_t)t * TILE_F2 + (size_t)L0 * 8 + rem];
            *(float4*)&ls[rem >> 3][t * 8 + (rem & 7)] = v;
        }
    }
    __syncthreads();

    int L = L0 + wv;

    float2 xb[7];
#pragma unroll
    for (int b = 0; b < 7; ++b) xb[b] = ls[wv][64 * b + lane];

    // twiddles W448^{lane*d7} (reused conjugated in the inverse pass)
    float2 tp[7];
#pragma unroll
    for (int d7 = 1; d7 < 7; ++d7) tp[d7] = t448[d7 * 64 + lane];

    // forward DFT7 (literal twiddles)
    float2 y[7];
#pragma unroll
    for (int d7 = 0; d7 < 7; ++d7) {
        float2 s = xb[0];
#pragma unroll
        for (int b = 1; b < 7; ++b) s = cfma_lit(xb[b], W7R[(b * d7) % 7], W7I[(b * d7) % 7], s);
        y[d7] = s;
    }
#pragma unroll
    for (int d7 = 1; d7 < 7; ++d7) y[d7] = cmul(y[d7], tp[d7]);

    // FFT64 across lanes, DIF (sign-trick): y' = (t + s*y) * weff
#pragma unroll
    for (int s = 0; s < 6; ++s) {
        int dist = 32 >> s;
        float2 wst = w64t[(lane & (dist - 1)) << s];
        bool hi = (lane & dist) != 0;
        float sg = hi ? -1.f : 1.f;
        float2 weff = hi ? wst : make_float2(1.f, 0.f);
#pragma unroll
        for (int d7 = 0; d7 < 7; ++d7) {
            float2 t = shflx2(y[d7], dist);
            float2 u = make_float2(fmaf(sg, y[d7].x, t.x), fmaf(sg, y[d7].y, t.y));
            y[d7] = cmul(u, weff);
        }
    }

    // mask: lane holds H-freq index 7*brev6(lane)+d7
    int rb = (brev5(lane & 31) << 1) | (lane >> 5);
    const float* mrow = maskP + (size_t)L * Hn + 7 * rb;
#pragma unroll
    for (int d7 = 0; d7 < 7; ++d7) {
        float m = mrow[d7];
        y[d7].x *= m; y[d7].y *= m;
    }

    // inverse FFT64, DIT (sign-trick): y' = A + c*B, c = +-conj(wst)
#pragma unroll
    for (int s = 0; s < 6; ++s) {
        int dist = 1 << s;
        float2 wst = w64t[(lane & (dist - 1)) << (5 - s)];
        wst.y = -wst.y;
        bool hi = (lane & dist) != 0;
        float2 c = hi ? make_float2(-wst.x, -wst.y) : wst;
#pragma unroll
        for (int d7 = 0; d7 < 7; ++d7) {
            float2 t = shflx2(y[d7], dist);
            float2 B = hi ? y[d7] : t;
            float2 A = hi ? t : y[d7];
            y[d7] = cfma(c, B, A);
        }
    }
    // conj W448 twiddle + inverse DFT7 (literal conj twiddles) + LDS writeback
#pragma unroll
    for (int d7 = 1; d7 < 7; ++d7) {
        float2 c = make_float2(tp[d7].x, -tp[d7].y);
        y[d7] = cmul(y[d7], c);
    }
#pragma unroll
    for (int b = 0; b < 7; ++b) {
        float2 s = y[0];
#pragma unroll
        for (int d7 = 1; d7 < 7; ++d7)
            s = cfma_lit(y[d7], W7R[(b * d7) % 7], -W7I[(b * d7) % 7], s);
        ls[wv][64 * b + lane] = s;
    }
    __syncthreads();

    // store: same tile-major addressing, float4, fully coalesced
#pragma unroll
    for (int m = 0; m < 4; ++m) {
        int j4 = tid + m * 256;
        if (j4 < 896) {
            int t = j4 >> 4, rem4 = j4 & 15;
            int rem = 2 * rem4;
            float4 v = *(const float4*)&ls[rem >> 3][t * 8 + (rem & 7)];
            *(float4*)&base[(size_t)t * TILE_F2 + (size_t)L0 * 8 + rem] = v;
        }
    }
}

// ---------- fused inverse row FFT + conj-coil + coil-sum + q/dot epilogue ----------
// Double-buffered LDS strips; strip loads are contiguous tile reads.
__global__ __launch_bounds__(256) void k_irow_combine(const float2* __restrict__ Y1T,
                                                      const float2* __restrict__ coil,
                                                      const float2* __restrict__ P,
                                                      float2* __restrict__ Q,
                                                      const float* __restrict__ miu,
                                                      double* __restrict__ S,
                                                      const float2* __restrict__ twg,
                                                      int cc, int chunkStart,
                                                      int first, int last, int it) {
    __shared__ float2 buf[2][8][BPITCH];
    __shared__ double sred[8];
    int tid = threadIdx.x;
    int lane = tid & 63, wv = tid >> 6, hi = lane >> 5, l32 = lane & 31;
    int h0 = blockIdx.x * 8, d = blockIdx.y;
    int row = h0 + 2 * wv + hi;
    const float2* w32g = twg + TW_W32;
    const float2* t224 = twg + TW_T224;

    float2 tp[7];
#pragma unroll
    for (int d7 = 1; d7 < 7; ++d7) {
        float2 v = t224[d7 * 32 + l32];
        tp[d7] = make_float2(v.x, -v.y);   // conj (inverse twiddle)
    }

    float2 acc[7];
#pragma unroll
    for (int b = 0; b < 7; ++b) acc[b] = make_float2(0.f, 0.f);

    // stage strip 0 into buf[0] — contiguous tile read
    float2 pre[7];
    {
        const float2* tile0 = Y1T + (size_t)d * HWn + (size_t)blockIdx.x * TILE_F2;
#pragma unroll
        for (int k = 0; k < 7; ++k) pre[k] = tile0[tid + k * 256];
#pragma unroll
        for (int k = 0; k < 7; ++k) {
            int i = tid + k * 256;
            buf[0][i & 7][i >> 3] = pre[k];
        }
    }
    __syncthreads();

    for (int cz = 0; cz < cc; ++cz) {
        int cur = cz & 1;
        // issue this coil's row loads FIRST (used at end of compute)
        const float2* crow = coil + (size_t)(chunkStart + cz) * HWn + (size_t)row * Wn;
        float2 cpre[7];
#pragma unroll
        for (int b = 0; b < 7; ++b) cpre[b] = crow[32 * b + l32];
        // then prefetch next strip (drains only at the ds_write below)
        if (cz + 1 < cc) {
            const float2* tilen = Y1T + ((size_t)(cz + 1) * Dn + d) * (size_t)HWn
                                + (size_t)blockIdx.x * TILE_F2;
#pragma unroll
            for (int k = 0; k < 7; ++k) pre[k] = tilen[tid + k * 256];
        }

        // lane l32 reads line L = d7*32 + l32 (DIT-ready bit-rev order)
        float2 y[7];
#pragma unroll
        for (int d7 = 0; d7 < 7; ++d7) y[d7] = buf[cur][2 * wv + hi][d7 * 32 + l32];

        // inverse FFT32 across half-wave, DIT (sign-trick): y' = A + c*B
#pragma unroll
        for (int s = 0; s < 5; ++s) {
            int dist = 1 << s;
            float2 wst = w32g[(l32 & (dist - 1)) << (4 - s)];
            wst.y = -wst.y;
            bool h2 = (l32 & dist) != 0;
            float2 c = h2 ? make_float2(-wst.x, -wst.y) : wst;
#pragma unroll
            for (int d7 = 0; d7 < 7; ++d7) {
                float2 t = shflx2(y[d7], dist);
                float2 B = h2 ? y[d7] : t;
                float2 A = h2 ? t : y[d7];
                y[d7] = cfma(c, B, A);
            }
        }
        // conj twiddle W224^{-l32*d7}
#pragma unroll
        for (int d7 = 1; d7 < 7; ++d7) y[d7] = cmul(y[d7], tp[d7]);
        // inverse DFT7 (literal conj twiddles) + conj-coil accumulate
#pragma unroll
        for (int b = 0; b < 7; ++b) {
            float2 s = y[0];
#pragma unroll
            for (int d7 = 1; d7 < 7; ++d7)
                s = cfma_lit(y[d7], W7R[(b * d7) % 7], -W7I[(b * d7) % 7], s);
            float2 c = cpre[b];
            acc[b].x += fmaf(s.x, c.x, s.y * c.y);
            acc[b].y += fmaf(s.y, c.x, -s.x * c.y);
        }

        // write next strip into the other buffer, one barrier per coil
        if (cz + 1 < cc) {
#pragma unroll
            for (int k = 0; k < 7; ++k) {
                int i = tid + k * 256;
                buf[cur ^ 1][i & 7][i >> 3] = pre[k];
            }
        }
        __syncthreads();
    }

    // epilogue: q = mu*p + acc (or q += acc), dots on last chunk
    float mu = fabsf(miu[0]);
    const float2* prow = P + (size_t)d * HWn + (size_t)row * Wn;
    float2* qrow = Q + (size_t)d * HWn + (size_t)row * Wn;
    double ar = 0.0, ai = 0.0;
#pragma unroll
    for (int b = 0; b < 7; ++b) {
        float2 pv = prow[32 * b + l32];
        float2 s0;
        if (first) s0 = make_float2(fmaf(mu, pv.x, acc[b].x), fmaf(mu, pv.y, acc[b].y));
        else { float2 qv = qrow[32 * b + l32]; s0 = cadd(qv, acc[b]); }
        qrow[32 * b + l32] = s0;
        if (last) {
            ar += (double)(s0.x * pv.x + s0.y * pv.y);
            ai += (double)(s0.y * pv.x - s0.x * pv.y);
        }
    }
    if (last) {
        ar = waveReduce(ar);
        ai = waveReduce(ai);
        if (lane == 0) { sred[wv] = ar; sred[4 + wv] = ai; }
        __syncthreads();
        if (tid == 0) {
            atomicAdd(&S[8 + it],  sred[0] + sred[1] + sred[2] + sred[3]);
            atomicAdd(&S[16 + it], sred[4] + sred[5] + sred[6] + sred[7]);
        }
    }
}

// ---------- CG scalar updates (float4 = 2 complex per lane) ----------
__global__ void k_update_br(const double* __restrict__ Sin, double* __restrict__ S, int it,
                            const float4* __restrict__ p, const float4* __restrict__ q,
                            float4* __restrict__ b, float4* __restrict__ r) {
    double rr = Sin[it], qr = Sin[8 + it], qi = Sin[16 + it];
    double den = qr * qr + qi * qi;
    float arf = (float)(rr * qr / den);
    float aif = (float)(-rr * qi / den);
    double acc = 0.0;
    const int N2 = DHWn / 2;
    for (int e = blockIdx.x * blockDim.x + threadIdx.x; e < N2; e += gridDim.x * blockDim.x) {
        float4 pv = p[e], qv = q[e], bv = b[e], rv = r[e];
        bv.x += arf * pv.x - aif * pv.y;  bv.y += arf * pv.y + aif * pv.x;
        bv.z += arf * pv.z - aif * pv.w;  bv.w += arf * pv.w + aif * pv.z;
        b[e] = bv;
        rv.x -= arf * qv.x - aif * qv.y;  rv.y -= arf * qv.y + aif * qv.x;
        rv.z -= arf * qv.z - aif * qv.w;  rv.w -= arf * qv.w + aif * qv.z;
        r[e] = rv;
        acc += (double)rv.x * rv.x + (double)rv.y * rv.y
             + (double)rv.z * rv.z + (double)rv.w * rv.w;
    }
    acc = waveReduce(acc);
    if ((threadIdx.x & 63) == 0) atomicAdd(&S[it + 1], acc);
}

__global__ void k_update_p(const double* __restrict__ S, int it,
                           const float4* __restrict__ r, float4* __restrict__ p) {
    float beta = (float)(S[it + 1] / S[it]);
    const int N2 = DHWn / 2;
    for (int e = blockIdx.x * blockDim.x + threadIdx.x; e < N2; e += gridDim.x * blockDim.x) {
        float4 rv = r[e], pv = p[e];
        p[e] = make_float4(fmaf(beta, pv.x, rv.x), fmaf(beta, pv.y, rv.y),
                           fmaf(beta, pv.z, rv.z), fmaf(beta, pv.w, rv.w));
    }
}

__global__ void k_output(const float2* __restrict__ b, float* __restrict__ out) {
    for (int e = blockIdx.x * blockDim.x + threadIdx.x; e < DHWn; e += gridDim.x * blockDim.x) {
        int d = e / HWn, rem = e - d * HWn;
        int h = rem / Wn, w = rem - h * Wn;
        int hs = h + Hn / 2; if (hs >= Hn) hs -= Hn;
        int ws = w + Wn / 2; if (ws >= Wn) ws -= Wn;
        float2 v = b[d * HWn + hs * Wn + ws];
        out[e] = v.x;
        out[DHWn + e] = v.y;
    }
}

extern "C" void kernel_launch(void* const* d_in, const int* in_sizes, int n_in,
                              void* d_out, int out_size, void* d_ws, size_t ws_size,
                              hipStream_t stream) {
    const float* z      = (const float*)d_in[0];
    const float* zf     = (const float*)d_in[1];
    const float* coil_r = (const float*)d_in[2];
    const float* coil_i = (const float*)d_in[3];
    const int*   maskp  = (const int*)d_in[4];
    const float* miu    = (const float*)d_in[5];
    float* out = (float*)d_out;

    char* w = (char*)d_ws;
    size_t off = 0;
    auto carve = [&](size_t bytes) -> void* {
        void* ptr = w + off;
        off += (bytes + 511) & ~(size_t)511;
        return ptr;
    };
    float2* P     = (float2*)carve((size_t)DHWn * 8);
    float2* R     = (float2*)carve((size_t)DHWn * 8);
    float2* Bv    = (float2*)carve((size_t)DHWn * 8);
    float2* Q     = (float2*)carve((size_t)DHWn * 8);
    float2* COIL  = (float2*)carve((size_t)Cn * HWn * 8);
    float*  MASKP = (float*)carve((size_t)HWn * 4);
    float2* TWS   = (float2*)carve(TW_NT * 8);
    double* S     = (double*)carve(64 * 8);

    size_t imgSet = (size_t)DHWn * 8;   // one coil-slot (12 slices), 9.63 MB
    int cc = 1;
    {
        const int opts[4] = {10, 5, 2, 1};
        for (int i = 0; i < 4; ++i) {
            if (off + (size_t)opts[i] * imgSet <= ws_size) { cc = opts[i]; break; }
        }
    }
    float2* Y1T = (float2*)carve((size_t)cc * imgSet);   // staged tiles [c][d][t][L][hh]
    int nch = Cn / cc;

    k_init_misc<<<1, 1024, 0, stream>>>(TWS, S);
    k_build_p<<<1024, 256, 0, stream>>>(z, zf, miu, P, R, Bv, S);
    k_build_coil<<<1024, 256, 0, stream>>>(coil_r, coil_i, COIL);
    k_build_mask<<<512, 256, 0, stream>>>(maskp, MASKP);

    for (int it = 0; it < 5; ++it) {
        for (int ch = 0; ch < nch; ++ch) {
            int cs = ch * cc;
            dim3 gf(Hn / 8, Dn, cc);    // 56 x 12 x cc
            dim3 gc(Wn / 4, Dn, cc);    // 56 x 12 x cc
            dim3 gi(Hn / 8, Dn);        // 56 x 12, loops over cc coils
            k_rowfft0<<<gf, 256, 0, stream>>>(P, COIL, Y1T, TWS, cs);
            k_colfft<<<gc, 256, 0, stream>>>(Y1T, MASKP, TWS);
            k_irow_combine<<<gi, 256, 0, stream>>>(Y1T, COIL, P, Q, miu, S, TWS,
                                                   cc, cs, ch == 0 ? 1 : 0,
                                                   ch == nch - 1 ? 1 : 0, it);
        }
        k_update_br<<<1024, 256, 0, stream>>>(S, S, it, (const float4*)P, (const float4*)Q,
                                              (float4*)Bv, (float4*)R);
        if (it < 4) k_update_p<<<1024, 256, 0, stream>>>(S, it, (const float4*)R, (float4*)P);
    }
    k_output<<<1024, 256, 0, stream>>>(Bv, out);
}